// Round 2
// 258.218 us; speedup vs baseline: 1.0083x; 1.0083x over previous
//
#include <hip/hip_runtime.h>

// Shapes (fixed by reference):
//   x : (32, 256, 64, 64) fp32   -> BS=32, C=256, HW=4096
//   w1: (32, 256)   b1: (32,)    -> HID=32
//   w2: (2, 512, 32) b2: (2,512) -> K=2, 2C=512
// out: (32, 256, 64, 64) fp32

#define BS   32
#define CCH  256
#define HW   4096
#define HID  32
#define KK   2

typedef float f4 __attribute__((ext_vector_type(4)));

// ---------------- Kernel 1: global average pool over (H,W) ----------------
// One block per (b,c) pair: 8192 blocks x 256 threads. 16 floats/thread via
// 4x float4 coalesced loads, shuffle reduce within wave64, LDS across waves.
// Normal (caching) loads on purpose: this pass populates the 256 MiB L3 with
// x (128 MiB) so the apply pass can read it from L3 instead of HBM.
__global__ __launch_bounds__(256) void pool_kernel(const float* __restrict__ x,
                                                   float* __restrict__ pooled) {
    const int bc = blockIdx.x;
    const float4* xp = (const float4*)(x + (size_t)bc * HW);
    const int t = threadIdx.x;
    float s = 0.f;
#pragma unroll
    for (int i = 0; i < 4; ++i) {
        float4 v = xp[t + i * 256];
        s += (v.x + v.y) + (v.z + v.w);
    }
    // wave64 reduction
#pragma unroll
    for (int off = 32; off > 0; off >>= 1)
        s += __shfl_down(s, off, 64);
    __shared__ float ws[4];
    if ((t & 63) == 0) ws[t >> 6] = s;
    __syncthreads();
    if (t == 0) {
        float tot = (ws[0] + ws[1]) + (ws[2] + ws[3]);
        pooled[bc] = tot * (1.0f / HW);
    }
}

// ---------------- Kernel 2: MLP + sigmoid -> per-(b,k,c) affine coeffs ----
// 32 blocks (one per batch) x 256 threads. FLOP count is tiny.
// h: 8 lanes per hidden unit (32 units x 8 lanes = 256 threads), width-8
// shuffle reduce (groups of 8 stay inside one wave64).
// A[b][k][c] = init_alpha[k] + 1.0 * (2*sigmoid(s_even)-1)
// B[b][k][c] = init_beta[k]  + 0.5 * (2*sigmoid(s_odd )-1)
__global__ __launch_bounds__(256) void coef_kernel(const float* __restrict__ pooled,
                                                   const float* __restrict__ w1,
                                                   const float* __restrict__ b1,
                                                   const float* __restrict__ w2,
                                                   const float* __restrict__ b2,
                                                   float* __restrict__ A,
                                                   float* __restrict__ Bc) {
    const int b = blockIdx.x;
    const int t = threadIdx.x;
    __shared__ float pl[CCH];
    __shared__ float h[HID];
    pl[t] = pooled[b * CCH + t];
    __syncthreads();
    {
        const int j = t >> 3;          // hidden unit 0..31
        const int l8 = t & 7;          // lane within group of 8
        const float* w1r = w1 + j * CCH + l8 * 32;
        const float* plr = pl + l8 * 32;
        float s = 0.f;
#pragma unroll
        for (int cdx = 0; cdx < 32; ++cdx) s += plr[cdx] * w1r[cdx];
#pragma unroll
        for (int off = 4; off > 0; off >>= 1)
            s += __shfl_down(s, off, 8);
        if (l8 == 0) h[j] = fmaxf(s + b1[j], 0.f);
    }
    __syncthreads();
    // 1024 (k,o) outputs, 256 threads -> 4 each
    for (int idx = t; idx < KK * 2 * CCH; idx += 256) {
        const int k = idx >> 9;       // / 512
        const int o = idx & 511;      // % 512
        float s = b2[k * 2 * CCH + o];
        const float* w2p = w2 + (size_t)(k * 2 * CCH + o) * HID;
#pragma unroll
        for (int j = 0; j < HID; ++j) s += w2p[j] * h[j];
        const float d = 2.f / (1.f + expf(-s)) - 1.f;   // 2*sigmoid-1
        const int c = o >> 1;
        const float initv = (k == 0) ? 1.f : 0.f;
        if ((o & 1) == 0)
            A[(b * KK + k) * CCH + c] = initv + 1.0f * d;   // LAMBDA_ALPHA=1.0
        else
            Bc[(b * KK + k) * CCH + c] = initv + 0.5f * d;  // LAMBDA_BETA=0.5
    }
}

// ---------------- Kernel 3: apply + max over K ----------------------------
// out = max(x*A0+B0, x*A1+B1). One block per (b,c) row: 8192 blocks x 256
// threads, 4 float4 per thread, coeffs loaded once per block (wave-uniform).
//
// KEY CHANGE vs round-0 version: non-temporal (nt) stores for `out` and nt
// loads for x. Without nt, out's write-allocations in the 256 MiB L3 evict
// the not-yet-read tail of x (x alone is 128 MiB, exactly half of L3), so a
// large fraction of x reads fell back to HBM. nt stores don't allocate ->
// x (fully resident after pool) is served from L3 and this kernel becomes
// HBM-write-bound (~134 MB written).
__global__ __launch_bounds__(256) void apply_kernel(const float* __restrict__ x,
                                                    const float* __restrict__ A,
                                                    const float* __restrict__ Bc,
                                                    float* __restrict__ out) {
    const int bc = blockIdx.x;            // (b,c) row, 8192 total
    const int b = bc >> 8;
    const int c = bc & 255;
    const float a0 = A[(b * 2 + 0) * CCH + c];
    const float a1 = A[(b * 2 + 1) * CCH + c];
    const float b0 = Bc[(b * 2 + 0) * CCH + c];
    const float b1 = Bc[(b * 2 + 1) * CCH + c];
    const f4* __restrict__ xp = (const f4*)(x + (size_t)bc * HW);
    f4* __restrict__ op = (f4*)(out + (size_t)bc * HW);
    const int t = threadIdx.x;
#pragma unroll
    for (int i = 0; i < 4; ++i) {
        const f4 v = __builtin_nontemporal_load(&xp[t + i * 256]);
        f4 r;
        r.x = fmaxf(v.x * a0 + b0, v.x * a1 + b1);
        r.y = fmaxf(v.y * a0 + b0, v.y * a1 + b1);
        r.z = fmaxf(v.z * a0 + b0, v.z * a1 + b1);
        r.w = fmaxf(v.w * a0 + b0, v.w * a1 + b1);
        __builtin_nontemporal_store(r, &op[t + i * 256]);
    }
}

extern "C" void kernel_launch(void* const* d_in, const int* in_sizes, int n_in,
                              void* d_out, int out_size, void* d_ws, size_t ws_size,
                              hipStream_t stream) {
    const float* x  = (const float*)d_in[0];
    const float* w1 = (const float*)d_in[1];
    const float* b1 = (const float*)d_in[2];
    const float* w2 = (const float*)d_in[3];
    const float* b2 = (const float*)d_in[4];
    float* out = (float*)d_out;

    // workspace layout (floats): pooled[8192] | A[32*2*256] | B[32*2*256]
    float* pooled = (float*)d_ws;
    float* A      = pooled + BS * CCH;
    float* Bc     = A + BS * KK * CCH;

    pool_kernel<<<BS * CCH, 256, 0, stream>>>(x, pooled);
    coef_kernel<<<BS, 256, 0, stream>>>(pooled, w1, b1, w2, b2, A, Bc);
    apply_kernel<<<BS * CCH, 256, 0, stream>>>(x, A, Bc, out);
}